// Round 1
// baseline (491.934 us; speedup 1.0000x reference)
//
#include <hip/hip_runtime.h>

// AttentiveConv3d: B=2, C=128, T=16, H=W=28, heads=2, HS=64, K=27 (3x3x3, pad 1)
// Round 0: correctness-first. One block (128 threads) per output position.
// Thread = channel. Taps staged in LDS; logits by 54 threads; softmax by 2;
// weighted sum + 128x128 projection by all 128 threads.

#define T_DIM 16
#define H_DIM 28
#define W_DIM 28
#define C_DIM 128
#define K_TAPS 27
#define HS 64

__global__ __launch_bounds__(128) void attn_conv3d_kernel(
    const float* __restrict__ x,     // [B, C, T, H, W]
    const float* __restrict__ q,     // [heads, 1, HS] -> q[h*HS + ch]
    const float* __restrict__ Wout,  // [C, C] row-major: Wout[co*C + ci]
    const float* __restrict__ bout,  // [C]
    float* __restrict__ out)         // [B, C, T, H, W]
{
    __shared__ float s_tap[K_TAPS][C_DIM];   // taps per channel
    __shared__ float s_logit[2 * K_TAPS];    // [k*2 + h]
    __shared__ float s_attn[2 * K_TAPS];
    __shared__ float s_merged[C_DIM];

    const int p = blockIdx.x;                 // position index over B*T*H*W
    const int v = p % W_DIM;
    const int u = (p / W_DIM) % H_DIM;
    const int t = (p / (W_DIM * H_DIM)) % T_DIM;
    const int b = p / (W_DIM * H_DIM * T_DIM);

    const int c = threadIdx.x;                // channel 0..127
    const int h = c & 1;                      // head = c % 2 (hs slow, heads fast)

    // ---- gather 27 taps for this channel (zero-padded) ----
    const float* xb = x + (size_t)(b * C_DIM + c) * (T_DIM * H_DIM * W_DIM);
    #pragma unroll
    for (int kk = 0; kk < K_TAPS; ++kk) {
        const int dt = kk / 9 - 1;
        const int du = (kk / 3) % 3 - 1;
        const int dv = kk % 3 - 1;
        const int tt = t + dt, uu = u + du, vv = v + dv;
        float val = 0.0f;
        if ((unsigned)tt < T_DIM && (unsigned)uu < H_DIM && (unsigned)vv < W_DIM)
            val = xb[(tt * H_DIM + uu) * W_DIM + vv];
        s_tap[kk][c] = val;
    }
    __syncthreads();

    // ---- logits: one thread per (k, head); effective scale 1/HS ----
    if (threadIdx.x < 2 * K_TAPS) {
        const int k  = threadIdx.x >> 1;
        const int hh = threadIdx.x & 1;
        float sum = 0.0f;
        #pragma unroll
        for (int ch = 0; ch < HS; ++ch)
            sum += q[hh * HS + ch] * s_tap[k][ch * 2 + hh];
        s_logit[threadIdx.x] = sum * (1.0f / (float)HS);
    }
    __syncthreads();

    // ---- softmax over k, per head ----
    if (threadIdx.x < 2) {
        const int hh = threadIdx.x;
        float m = -1e30f;
        for (int k = 0; k < K_TAPS; ++k) m = fmaxf(m, s_logit[k * 2 + hh]);
        float s = 0.0f;
        for (int k = 0; k < K_TAPS; ++k) {
            const float e = expf(s_logit[k * 2 + hh] - m);
            s_attn[k * 2 + hh] = e;
            s += e;
        }
        const float inv = 1.0f / s;
        for (int k = 0; k < K_TAPS; ++k) s_attn[k * 2 + hh] *= inv;
    }
    __syncthreads();

    // ---- attention-weighted tap sum ----
    float acc = 0.0f;
    #pragma unroll
    for (int k = 0; k < K_TAPS; ++k)
        acc += s_attn[k * 2 + h] * s_tap[k][c];
    s_merged[c] = acc;
    __syncthreads();

    // ---- output projection: y[co] = b[co] + sum_ci Wout[co][ci]*merged[ci] ----
    float y = bout[c];
    const float* wrow = Wout + c * C_DIM;
    #pragma unroll 8
    for (int ci = 0; ci < C_DIM; ++ci)
        y += wrow[ci] * s_merged[ci];

    out[((size_t)(b * C_DIM + c) * T_DIM + t) * (H_DIM * W_DIM) + u * W_DIM + v] = y;
}

extern "C" void kernel_launch(void* const* d_in, const int* in_sizes, int n_in,
                              void* d_out, int out_size, void* d_ws, size_t ws_size,
                              hipStream_t stream) {
    const float* x    = (const float*)d_in[0];
    const float* q    = (const float*)d_in[1];
    const float* Wout = (const float*)d_in[2];
    const float* bout = (const float*)d_in[3];
    float* out = (float*)d_out;

    const int n_pos = 2 * T_DIM * H_DIM * W_DIM;  // 25088
    attn_conv3d_kernel<<<dim3(n_pos), dim3(128), 0, stream>>>(x, q, Wout, bout, out);
}

// Round 2
// 142.317 us; speedup vs baseline: 3.4566x; 3.4566x over previous
//
#include <hip/hip_runtime.h>

// AttentiveConv3d: B=2, C=128, T=16, H=W=28, heads=2, HS=64, K=27 (3x3x3, pad 1)
// Round 2: two-kernel restructure.
//   K1: s[h][p] = sum_c q~[h,c] * x[b,c,p]   (logit field, 200KB in d_ws)
//   K2: per (b,t,u)-row block: softmax over 27 s-neighbors -> attn in LDS;
//       merged[c][v] = sum_k attn*x (coalesced along v, OOB folded into weight);
//       128x128 projection with W staged in LDS (2 passes of 64 rows).

#define TT 16
#define HH 28
#define WW 28
#define CC 128
#define SP (TT * HH * WW)   // 12544
#define NPOS (2 * SP)       // 25088
#define HS 64
#define KT 27

__global__ __launch_bounds__(256) void qfield_kernel(
    const float* __restrict__ x, const float* __restrict__ q,
    float* __restrict__ s)
{
    __shared__ float sp[16][32];     // [h*8+g][pos_local]
    const int tid = threadIdx.x;
    const int pl  = tid & 31;
    const int g   = tid >> 5;        // channel group 0..7
    const int p   = blockIdx.x * 32 + pl;
    const int b   = p / SP;
    const int si  = p % SP;
    const float* xb = x + (size_t)b * CC * SP + si;

    float acc0 = 0.f, acc1 = 0.f;    // head 0 / head 1 partials
    #pragma unroll
    for (int j = 0; j < 16; ++j) {
        const int c = g * 16 + j;              // channel
        const float val = xb[(size_t)c * SP];
        const float qv  = q[(c & 1) * HS + (c >> 1)] * (1.0f / 64.0f);
        if (c & 1) acc1 += qv * val; else acc0 += qv * val;
    }
    sp[g][pl]     = acc0;
    sp[8 + g][pl] = acc1;
    __syncthreads();
    if (tid < 64) {
        const int h = tid >> 5, pp = tid & 31;
        float a = 0.f;
        #pragma unroll
        for (int g2 = 0; g2 < 8; ++g2) a += sp[h * 8 + g2][pp];
        s[h * NPOS + blockIdx.x * 32 + pp] = a;
    }
}

__global__ __launch_bounds__(256) void attnconv_kernel(
    const float* __restrict__ x, const float* __restrict__ s,
    const float* __restrict__ Wout, const float* __restrict__ bout,
    float* __restrict__ out)
{
    __shared__ float s_attn[KT][2][HH];   // [k][h][v]   6 KB
    __shared__ float s_mrg[CC][WW];       // [ci][v]    14 KB
    __shared__ float s_w[64][CC];         // W half     32 KB

    const int blk = blockIdx.x;           // over (b, t, u)
    const int u   = blk % HH;
    const int t   = (blk / HH) % TT;
    const int b   = blk / (HH * TT);
    const int tid  = threadIdx.x;
    const int lane = tid & 31;            // v (active if < 28)
    const int g    = tid >> 5;            // 0..7

    // ---- phase A: attention weights from the s-field ----
    if (tid < 2 * WW) {
        const int h = tid & 1, v = tid >> 1;
        float l[KT];
        #pragma unroll
        for (int k = 0; k < KT; ++k) {
            const int dt = k / 9 - 1, du = (k / 3) % 3 - 1, dv = k % 3 - 1;
            const int tt = t + dt, uu = u + du, vv = v + dv;
            float val = 0.f;   // OOB tap => x=0 => logit 0 (matches reference pad)
            if ((unsigned)tt < TT && (unsigned)uu < HH && (unsigned)vv < WW)
                val = s[h * NPOS + b * SP + (tt * HH + uu) * WW + vv];
            l[k] = val;
        }
        float m = l[0];
        #pragma unroll
        for (int k = 1; k < KT; ++k) m = fmaxf(m, l[k]);
        float sum = 0.f;
        #pragma unroll
        for (int k = 0; k < KT; ++k) { l[k] = expf(l[k] - m); sum += l[k]; }
        const float inv = 1.f / sum;
        #pragma unroll
        for (int k = 0; k < KT; ++k) s_attn[k][h][v] = l[k] * inv;
    }
    __syncthreads();

    // ---- phase B: merged[c][v] = sum_k attn[k,h(c),v] * x[c, p+off_k] ----
    if (lane < WW) {
        const int h = g & 1;              // c = g + 8i  =>  c&1 == g&1
        int   off[KT];
        float aw[KT];
        #pragma unroll
        for (int k = 0; k < KT; ++k) {
            const int dt = k / 9 - 1, du = (k / 3) % 3 - 1, dv = k % 3 - 1;
            const int tt = t + dt, uu = u + du, vv = lane + dv;
            const bool ok = (unsigned)tt < TT && (unsigned)uu < HH && (unsigned)vv < WW;
            off[k] = ok ? (tt * HH + uu) * WW + vv : 0;
            aw[k]  = ok ? s_attn[k][h][lane] : 0.f;   // OOB value folded to 0
        }
        for (int i = 0; i < 16; ++i) {
            const int c = g + 8 * i;
            const float* xc = x + (size_t)(b * CC + c) * SP;
            float a = 0.f;
            #pragma unroll
            for (int k = 0; k < KT; ++k) a += aw[k] * xc[off[k]];
            s_mrg[c][lane] = a;
        }
    }
    __syncthreads();

    // ---- phase C: y[co][v] = b[co] + sum_ci W[co][ci]*merged[ci][v] ----
    const size_t obase = (size_t)b * CC * SP + (size_t)(t * HH + u) * WW + lane;
    for (int pass = 0; pass < 2; ++pass) {
        // stage 64 W rows into LDS (coalesced float4)
        const float4* wsrc = (const float4*)(Wout + (size_t)pass * 64 * CC);
        float4* wdst = (float4*)(&s_w[0][0]);
        for (int j = tid; j < 64 * CC / 4; j += 256) wdst[j] = wsrc[j];
        __syncthreads();
        if (lane < WW) {
            float acc[8];
            #pragma unroll
            for (int j2 = 0; j2 < 8; ++j2) acc[j2] = bout[pass * 64 + g * 8 + j2];
            #pragma unroll 8
            for (int ci = 0; ci < CC; ci += 4) {
                const float m0 = s_mrg[ci    ][lane];
                const float m1 = s_mrg[ci + 1][lane];
                const float m2 = s_mrg[ci + 2][lane];
                const float m3 = s_mrg[ci + 3][lane];
                #pragma unroll
                for (int j2 = 0; j2 < 8; ++j2) {
                    const float4 w = *(const float4*)&s_w[g * 8 + j2][ci];
                    acc[j2] += w.x * m0 + w.y * m1 + w.z * m2 + w.w * m3;
                }
            }
            #pragma unroll
            for (int j2 = 0; j2 < 8; ++j2) {
                const int co = pass * 64 + g * 8 + j2;
                out[obase + (size_t)co * SP] = acc[j2];
            }
        }
        __syncthreads();
    }
}

extern "C" void kernel_launch(void* const* d_in, const int* in_sizes, int n_in,
                              void* d_out, int out_size, void* d_ws, size_t ws_size,
                              hipStream_t stream) {
    const float* x    = (const float*)d_in[0];
    const float* q    = (const float*)d_in[1];
    const float* Wout = (const float*)d_in[2];
    const float* bout = (const float*)d_in[3];
    float* out = (float*)d_out;
    float* s   = (float*)d_ws;                 // 2 * 25088 floats = 200 KB

    qfield_kernel<<<dim3(NPOS / 32), dim3(256), 0, stream>>>(x, q, s);
    attnconv_kernel<<<dim3(2 * TT * HH), dim3(256), 0, stream>>>(x, s, Wout, bout, out);
}

// Round 3
// 122.611 us; speedup vs baseline: 4.0121x; 1.1607x over previous
//
#include <hip/hip_runtime.h>

// AttentiveConv3d: B=2, C=128, T=16, H=W=28, heads=2, HS=64, K=27 (3x3x3, pad 1)
// Round 3: drop W LDS staging (global broadcast via L1/L2), transpose merged
// buffer for float4 phase-C reads, 4co x 4v register blocking.
//   K1: s[h][p] = sum_c q~[h,c] * x[b,c,p]   (logit field, 200KB in d_ws)
//   K2: per (b,t,u)-row block: softmax -> attn in LDS; merged[v][ci] in LDS;
//       projection y = W*merged + b with register tiling.

#define TT 16
#define HH 28
#define WW 28
#define CC 128
#define SP (TT * HH * WW)   // 12544
#define NPOS (2 * SP)       // 25088
#define HS 64
#define KT 27
#define MSTR 129            // padded stride for s_mrg_t

__global__ __launch_bounds__(256) void qfield_kernel(
    const float* __restrict__ x, const float* __restrict__ q,
    float* __restrict__ s)
{
    __shared__ float sp[16][32];     // [h*8+g][pos_local]
    const int tid = threadIdx.x;
    const int pl  = tid & 31;
    const int g   = tid >> 5;        // channel group 0..7
    const int p   = blockIdx.x * 32 + pl;
    const int b   = p / SP;
    const int si  = p % SP;
    const float* xb = x + (size_t)b * CC * SP + si;

    float acc0 = 0.f, acc1 = 0.f;    // head 0 / head 1 partials
    #pragma unroll
    for (int j = 0; j < 16; ++j) {
        const int c = g * 16 + j;              // channel
        const float val = xb[(size_t)c * SP];
        const float qv  = q[(c & 1) * HS + (c >> 1)] * (1.0f / 64.0f);
        if (c & 1) acc1 += qv * val; else acc0 += qv * val;
    }
    sp[g][pl]     = acc0;
    sp[8 + g][pl] = acc1;
    __syncthreads();
    if (tid < 64) {
        const int h = tid >> 5, pp = tid & 31;
        float a = 0.f;
        #pragma unroll
        for (int g2 = 0; g2 < 8; ++g2) a += sp[h * 8 + g2][pp];
        s[h * NPOS + blockIdx.x * 32 + pp] = a;
    }
}

__global__ __launch_bounds__(256) void attnconv_kernel(
    const float* __restrict__ x, const float* __restrict__ s,
    const float* __restrict__ Wout, const float* __restrict__ bout,
    float* __restrict__ out)
{
    __shared__ float s_attn[KT][2][HH];    // [k][h][v]     ~6 KB
    __shared__ float s_mrg_t[WW][MSTR];    // [v][ci] pad  ~14.4 KB

    const int blk = blockIdx.x;            // over (b, t, u)
    const int u   = blk % HH;
    const int t   = (blk / HH) % TT;
    const int b   = blk / (HH * TT);
    const int tid  = threadIdx.x;
    const int lane = tid & 31;             // v (active if < 28)
    const int g    = tid >> 5;             // 0..7

    // ---- phase A: attention weights from the s-field ----
    if (tid < 2 * WW) {
        const int h = tid & 1, v = tid >> 1;
        float l[KT];
        #pragma unroll
        for (int k = 0; k < KT; ++k) {
            const int dt = k / 9 - 1, du = (k / 3) % 3 - 1, dv = k % 3 - 1;
            const int tt = t + dt, uu = u + du, vv = v + dv;
            float val = 0.f;   // OOB tap => x=0 => logit 0 (matches reference pad)
            if ((unsigned)tt < TT && (unsigned)uu < HH && (unsigned)vv < WW)
                val = s[h * NPOS + b * SP + (tt * HH + uu) * WW + vv];
            l[k] = val;
        }
        float m = l[0];
        #pragma unroll
        for (int k = 1; k < KT; ++k) m = fmaxf(m, l[k]);
        float sum = 0.f;
        #pragma unroll
        for (int k = 0; k < KT; ++k) { l[k] = __expf(l[k] - m); sum += l[k]; }
        const float inv = 1.f / sum;
        #pragma unroll
        for (int k = 0; k < KT; ++k) s_attn[k][h][v] = l[k] * inv;
    }
    __syncthreads();

    // ---- phase B: s_mrg_t[v][c] = sum_k attn[k,h(c),v] * x[c, p+off_k] ----
    if (lane < WW) {
        const int h = g & 1;               // c = g + 8i  =>  c&1 == g&1
        int   off[KT];
        float aw[KT];
        #pragma unroll
        for (int k = 0; k < KT; ++k) {
            const int dt = k / 9 - 1, du = (k / 3) % 3 - 1, dv = k % 3 - 1;
            const int tt = t + dt, uu = u + du, vv = lane + dv;
            const bool ok = (unsigned)tt < TT && (unsigned)uu < HH && (unsigned)vv < WW;
            off[k] = ok ? (tt * HH + uu) * WW + vv : 0;
            aw[k]  = ok ? s_attn[k][h][lane] : 0.f;   // OOB folded to 0
        }
        #pragma unroll 4
        for (int i = 0; i < 16; ++i) {
            const int c = g + 8 * i;
            const float* xc = x + (size_t)(b * CC + c) * SP;
            float a = 0.f;
            #pragma unroll
            for (int k = 0; k < KT; ++k) a += aw[k] * xc[off[k]];
            s_mrg_t[lane][c] = a;
        }
    }
    __syncthreads();

    // ---- phase C: y[co][v] = b[co] + sum_ci W[co][ci]*merged[v][ci] ----
    // thread -> 4 co x 4 v register tile: cog = tid>>3 (co=4*cog..), vg = tid&7
    const int cog = tid >> 3;              // 0..31
    const int vg  = tid & 7;               // 0..7, active if < 7
    if (vg < 7) {
        const float4* wrow0 = (const float4*)(Wout + (size_t)(cog * 4 + 0) * CC);
        const float4* wrow1 = (const float4*)(Wout + (size_t)(cog * 4 + 1) * CC);
        const float4* wrow2 = (const float4*)(Wout + (size_t)(cog * 4 + 2) * CC);
        const float4* wrow3 = (const float4*)(Wout + (size_t)(cog * 4 + 3) * CC);

        float acc[4][4];
        #pragma unroll
        for (int c = 0; c < 4; ++c) {
            const float bb = bout[cog * 4 + c];
            #pragma unroll
            for (int p = 0; p < 4; ++p) acc[c][p] = bb;
        }

        #pragma unroll 8
        for (int q4 = 0; q4 < CC / 4; ++q4) {
            float4 m4[4];
            #pragma unroll
            for (int p = 0; p < 4; ++p)
                m4[p] = *(const float4*)&s_mrg_t[vg * 4 + p][q4 * 4];
            float4 w4[4];
            w4[0] = wrow0[q4]; w4[1] = wrow1[q4]; w4[2] = wrow2[q4]; w4[3] = wrow3[q4];
            #pragma unroll
            for (int c = 0; c < 4; ++c)
                #pragma unroll
                for (int p = 0; p < 4; ++p)
                    acc[c][p] += w4[c].x * m4[p].x + w4[c].y * m4[p].y
                               + w4[c].z * m4[p].z + w4[c].w * m4[p].w;
        }

        const size_t obase = (size_t)b * CC * SP + (size_t)(t * HH + u) * WW;
        #pragma unroll
        for (int c = 0; c < 4; ++c) {
            const int co = cog * 4 + c;
            #pragma unroll
            for (int p = 0; p < 4; ++p)
                out[obase + (size_t)co * SP + vg * 4 + p] = acc[c][p];
        }
    }
}

extern "C" void kernel_launch(void* const* d_in, const int* in_sizes, int n_in,
                              void* d_out, int out_size, void* d_ws, size_t ws_size,
                              hipStream_t stream) {
    const float* x    = (const float*)d_in[0];
    const float* q    = (const float*)d_in[1];
    const float* Wout = (const float*)d_in[2];
    const float* bout = (const float*)d_in[3];
    float* out = (float*)d_out;
    float* s   = (float*)d_ws;                 // 2 * 25088 floats = 200 KB

    qfield_kernel<<<dim3(NPOS / 32), dim3(256), 0, stream>>>(x, q, s);
    attnconv_kernel<<<dim3(2 * TT * HH), dim3(256), 0, stream>>>(x, s, Wout, bout, out);
}

// Round 4
// 67.786 us; speedup vs baseline: 7.2572x; 1.8088x over previous
//
#include <hip/hip_runtime.h>

// AttentiveConv3d: B=2, C=128, T=16, H=W=28, heads=2, HS=64, K=27 (3x3x3, pad 1)
// Round 4: barrier-free 4-kernel decomposition through d_ws.
//   K1 qfield : s[h][b][p] = sum_c q~[h,c] * x[b,c,p]              (200 KB)
//   K2 aweight: aw[b][h][k][p] = softmax_k over s-neighborhood,
//               OOB taps get weight 0 (logit 0 kept in the sum)    (5.4 MB)
//   K3 merge  : merged[b][c][p] = sum_k aw[h(c)][k][p] * x[c,p+off] (12.8 MB)
//   K4 proj   : out = W @ merged + b   (GEMM, 32-p tiles, LDS merged tile)

#define TT 16
#define HH 28
#define WW 28
#define CC 128
#define SP (TT * HH * WW)   // 12544 = 49*256, 392*32
#define NPOS (2 * SP)       // 25088
#define HS 64
#define KT 27

__global__ __launch_bounds__(256) void qfield_kernel(
    const float* __restrict__ x, const float* __restrict__ q,
    float* __restrict__ s)
{
    __shared__ float sp[16][32];     // [h*8+g][pos_local]
    const int tid = threadIdx.x;
    const int pl  = tid & 31;
    const int g   = tid >> 5;        // channel group 0..7
    const int p   = blockIdx.x * 32 + pl;
    const int b   = p / SP;
    const int si  = p % SP;
    const float* xb = x + (size_t)b * CC * SP + si;

    float acc0 = 0.f, acc1 = 0.f;    // head 0 / head 1 partials
    #pragma unroll
    for (int j = 0; j < 16; ++j) {
        const int c = g * 16 + j;              // channel
        const float val = xb[(size_t)c * SP];
        const float qv  = q[(c & 1) * HS + (c >> 1)] * (1.0f / 64.0f);
        if (c & 1) acc1 += qv * val; else acc0 += qv * val;
    }
    sp[g][pl]     = acc0;
    sp[8 + g][pl] = acc1;
    __syncthreads();
    if (tid < 64) {
        const int h = tid >> 5, pp = tid & 31;
        float a = 0.f;
        #pragma unroll
        for (int g2 = 0; g2 < 8; ++g2) a += sp[h * 8 + g2][pp];
        s[h * NPOS + blockIdx.x * 32 + pp] = a;
    }
}

// thread = (b, h, p);  aw[((b*2+h)*KT + k)*SP + p]
__global__ __launch_bounds__(256) void aweight_kernel(
    const float* __restrict__ s, float* __restrict__ aw)
{
    const int idx = blockIdx.x * 256 + threadIdx.x;   // 4*SP = 50176 exactly
    const int p = idx % SP;
    const int h = (idx / SP) & 1;
    const int b = idx / (2 * SP);
    const int v = p % WW, u = (p / WW) % HH, t = p / (WW * HH);
    const float* sf = s + h * NPOS + b * SP;

    float l[KT], msk[KT];
    #pragma unroll
    for (int k = 0; k < KT; ++k) {
        const int dt = k / 9 - 1, du = (k / 3) % 3 - 1, dv = k % 3 - 1;
        const int tt = t + dt, uu = u + du, vv = v + dv;
        const bool ok = (unsigned)tt < TT && (unsigned)uu < HH && (unsigned)vv < WW;
        l[k]   = ok ? sf[(tt * HH + uu) * WW + vv] : 0.f;  // OOB logit = 0 (pad)
        msk[k] = ok ? 1.f : 0.f;
    }
    float m = l[0];
    #pragma unroll
    for (int k = 1; k < KT; ++k) m = fmaxf(m, l[k]);
    float sum = 0.f;
    #pragma unroll
    for (int k = 0; k < KT; ++k) { l[k] = __expf(l[k] - m); sum += l[k]; }
    const float inv = 1.f / sum;
    float* awp = aw + (size_t)(b * 2 + h) * KT * SP + p;
    #pragma unroll
    for (int k = 0; k < KT; ++k)
        awp[(size_t)k * SP] = l[k] * inv * msk[k];   // OOB weight folded to 0
}

// thread = (b, c, p), p fastest (SP = 49*256 -> block covers 256 p in one (b,c))
__global__ __launch_bounds__(256) void merge_kernel(
    const float* __restrict__ x, const float* __restrict__ aw,
    float* __restrict__ mrg)
{
    const int idx = blockIdx.x * 256 + threadIdx.x;
    const int p = idx % SP;
    const int c = (idx / SP) % CC;
    const int b = idx / (CC * SP);
    const int h = c & 1;
    const int v = p % WW, u = (p / WW) % HH, t = p / (WW * HH);
    const float* xc  = x + (size_t)(b * CC + c) * SP;
    const float* awp = aw + (size_t)(b * 2 + h) * KT * SP + p;

    float acc = 0.f;
    #pragma unroll
    for (int k = 0; k < KT; ++k) {
        const int dt = k / 9 - 1, du = (k / 3) % 3 - 1, dv = k % 3 - 1;
        const int tt = t + dt, uu = u + du, vv = v + dv;
        const bool ok = (unsigned)tt < TT && (unsigned)uu < HH && (unsigned)vv < WW;
        const int off = ok ? (tt * HH + uu) * WW + vv : p;  // safe addr; aw=0 if OOB
        acc += awp[(size_t)k * SP] * xc[off];
    }
    mrg[idx] = acc;
}

// block = 32-p tile of one batch; 256 threads = (cog 0..31) x (vg 0..7)
__global__ __launch_bounds__(256) void proj_kernel(
    const float* __restrict__ mrg, const float* __restrict__ Wout,
    const float* __restrict__ bout, float* __restrict__ out)
{
    __shared__ float s_m[CC][32];          // 16 KB
    const int pb  = blockIdx.x;            // 2 * 392
    const int b   = pb / (SP / 32);
    const int p0  = (pb % (SP / 32)) * 32;
    const int tid = threadIdx.x;

    // stage merged[128][p0..p0+32) -> LDS, fully coalesced float4
    const float4* src = (const float4*)(mrg + (size_t)b * CC * SP);
    float4* dst = (float4*)&s_m[0][0];
    #pragma unroll
    for (int j = tid; j < CC * 8; j += 256) {
        const int ci = j >> 3, col = j & 7;
        dst[j] = src[(size_t)ci * (SP / 4) + p0 / 4 + col];
    }
    __syncthreads();

    const int cog = tid >> 3;              // co = cog*4 + c
    const int vg  = tid & 7;               // p = p0 + vg*4 + (vec lane)
    const float4* w0 = (const float4*)(Wout + (size_t)(cog * 4 + 0) * CC);
    const float4* w1 = (const float4*)(Wout + (size_t)(cog * 4 + 1) * CC);
    const float4* w2 = (const float4*)(Wout + (size_t)(cog * 4 + 2) * CC);
    const float4* w3 = (const float4*)(Wout + (size_t)(cog * 4 + 3) * CC);

    float4 acc[4];
    #pragma unroll
    for (int c = 0; c < 4; ++c) {
        const float bb = bout[cog * 4 + c];
        acc[c] = make_float4(bb, bb, bb, bb);
    }

    #pragma unroll 8
    for (int q4 = 0; q4 < CC / 4; ++q4) {
        float4 w4[4] = { w0[q4], w1[q4], w2[q4], w3[q4] };
        float4 m0 = *(const float4*)&s_m[q4 * 4 + 0][vg * 4];
        float4 m1 = *(const float4*)&s_m[q4 * 4 + 1][vg * 4];
        float4 m2 = *(const float4*)&s_m[q4 * 4 + 2][vg * 4];
        float4 m3 = *(const float4*)&s_m[q4 * 4 + 3][vg * 4];
        #pragma unroll
        for (int c = 0; c < 4; ++c) {
            acc[c].x += w4[c].x * m0.x + w4[c].y * m1.x + w4[c].z * m2.x + w4[c].w * m3.x;
            acc[c].y += w4[c].x * m0.y + w4[c].y * m1.y + w4[c].z * m2.y + w4[c].w * m3.y;
            acc[c].z += w4[c].x * m0.z + w4[c].y * m1.z + w4[c].z * m2.z + w4[c].w * m3.z;
            acc[c].w += w4[c].x * m0.w + w4[c].y * m1.w + w4[c].z * m2.w + w4[c].w * m3.w;
        }
    }

    #pragma unroll
    for (int c = 0; c < 4; ++c) {
        const int co = cog * 4 + c;
        *(float4*)&out[(size_t)(b * CC + co) * SP + p0 + vg * 4] = acc[c];
    }
}

extern "C" void kernel_launch(void* const* d_in, const int* in_sizes, int n_in,
                              void* d_out, int out_size, void* d_ws, size_t ws_size,
                              hipStream_t stream) {
    const float* x    = (const float*)d_in[0];
    const float* q    = (const float*)d_in[1];
    const float* Wout = (const float*)d_in[2];
    const float* bout = (const float*)d_in[3];
    float* out = (float*)d_out;

    float* s   = (float*)d_ws;                       // 50176 floats
    float* aw  = s + NPOS;                           // 2*2*27*SP = 1354752 floats
    float* mrg = aw + (size_t)4 * KT * SP;           // 2*128*SP  = 3211264 floats

    qfield_kernel <<<dim3(NPOS / 32),        dim3(256), 0, stream>>>(x, q, s);
    aweight_kernel<<<dim3(4 * SP / 256),     dim3(256), 0, stream>>>(s, aw);
    merge_kernel  <<<dim3(2 * CC * SP / 256),dim3(256), 0, stream>>>(x, aw, mrg);
    proj_kernel   <<<dim3(2 * (SP / 32)),    dim3(256), 0, stream>>>(mrg, Wout, bout, out);
}